// Round 19
// baseline (395.963 us; speedup 1.0000x reference)
//
#include <hip/hip_runtime.h>
#include <math.h>

#define NB 32768   // batch
// D=256, N=4, OUT=512, H=4, DH=64

typedef unsigned short u16;
typedef __attribute__((ext_vector_type(4))) float f32x4;
typedef __attribute__((ext_vector_type(8))) short bf16x8;

__device__ __forceinline__ float bf2f(u16 u){ return __uint_as_float(((unsigned int)u)<<16); }
__device__ __forceinline__ u16 f2bf(float f){
    unsigned int x = __float_as_uint(f);
    x += 0x7fffu + ((x>>16)&1u);   // round-to-nearest-even
    return (u16)(x>>16);
}
// gelu exact-erf via A&S 7.1.26 (|eps|<=1.5e-7), branchless: rcp + exp + 5 fma
__device__ __forceinline__ float gelu_f(float x){
    float z = fabsf(x) * 0.70710678118654752f;
    float t = __builtin_amdgcn_rcpf(1.0f + 0.3275911f*z);
    float p = t*(0.254829592f + t*(-0.284496736f + t*(1.421413741f + t*(-1.453152027f + t*1.061405429f))));
    float e = __expf(-z*z);
    float erf_abs = 1.0f - p*e;
    float erfv = copysignf(erf_abs, x);
    return 0.5f*x*(1.0f + erfv);
}

__device__ __forceinline__ void gload16(const void* g, void* l){
    __builtin_amdgcn_global_load_lds(
        (const __attribute__((address_space(1))) unsigned int*)g,
        (__attribute__((address_space(3))) unsigned int*)l, 16, 0, 0);
}

// ---------------- prep (scale w0..w3 by softmax(tfw)) + all weight fp32->bf16 conversions ----------------
__global__ __launch_bounds__(256) void prepconv_kernel(
    const float* __restrict__ w0, const float* __restrict__ w1,
    const float* __restrict__ w2, const float* __restrict__ w3,
    const float* __restrict__ tfw, u16* __restrict__ wcat,
    const float* __restrict__ ipw_s, u16* __restrict__ ipw_d,
    const float* __restrict__ op_s,  u16* __restrict__ op_d,
    const float* __restrict__ f1_s,  u16* __restrict__ f1_d,
    const float* __restrict__ f2_s,  u16* __restrict__ f2_d,
    const float* __restrict__ a1_s,  u16* __restrict__ a1_d)
{
    const int blk = blockIdx.x, tid = threadIdx.x;
    if (blk < 8192){
        float t0=tfw[0], t1=tfw[1], t2=tfw[2], t3=tfw[3];
        float m = fmaxf(fmaxf(t0,t1), fmaxf(t2,t3));
        float e0=expf(t0-m), e1=expf(t1-m), e2=expf(t2-m), e3=expf(t3-m);
        float inv = 1.0f/(e0+e1+e2+e3);
        float s0=e0*inv, s1=e1*inv, s2=e2*inv, s3=e3*inv;

        int idx = blk*256 + tid;
        int b  = idx >> 6;
        int d4 = (idx & 63) << 2;
        size_t src = (size_t)b*256 + d4;
        float4 a0 = *reinterpret_cast<const float4*>(w0 + src);
        float4 a1 = *reinterpret_cast<const float4*>(w1 + src);
        float4 a2 = *reinterpret_cast<const float4*>(w2 + src);
        float4 a3 = *reinterpret_cast<const float4*>(w3 + src);
        size_t dst = (size_t)b*1024 + d4;
        ushort4 o;
        o.x=f2bf(a0.x*s0); o.y=f2bf(a0.y*s0); o.z=f2bf(a0.z*s0); o.w=f2bf(a0.w*s0);
        *reinterpret_cast<ushort4*>(wcat + dst) = o;
        o.x=f2bf(a1.x*s1); o.y=f2bf(a1.y*s1); o.z=f2bf(a1.z*s1); o.w=f2bf(a1.w*s1);
        *reinterpret_cast<ushort4*>(wcat + dst + 256) = o;
        o.x=f2bf(a2.x*s2); o.y=f2bf(a2.y*s2); o.z=f2bf(a2.z*s2); o.w=f2bf(a2.w*s2);
        *reinterpret_cast<ushort4*>(wcat + dst + 512) = o;
        o.x=f2bf(a3.x*s3); o.y=f2bf(a3.y*s3); o.z=f2bf(a3.z*s3); o.w=f2bf(a3.w*s3);
        *reinterpret_cast<ushort4*>(wcat + dst + 768) = o;
    } else {
        int i = (blk - 8192)*256 + tid;   // float4 index across all weights
        const float* s; u16* d; int off;
        if      (i < 49152)  { s=ipw_s; d=ipw_d; off=i; }
        else if (i < 65536)  { s=op_s;  d=op_d;  off=i-49152; }
        else if (i < 327680) { s=f1_s;  d=f1_d;  off=i-65536; }
        else if (i < 458752) { s=f2_s;  d=f2_d;  off=i-327680; }
        else                 { s=a1_s;  d=a1_d;  off=i-458752; }
        float4 v = reinterpret_cast<const float4*>(s)[off];
        ushort4 o; o.x=f2bf(v.x); o.y=f2bf(v.y); o.z=f2bf(v.z); o.w=f2bf(v.w);
        reinterpret_cast<ushort4*>(d)[off] = o;
    }
}

// ---------------- 128x128 MFMA GEMM. ACT: 0 none, 1 gelu, 2 gelu + fused a2 row-dot ----------------
template<int ACT>
__global__ __launch_bounds__(256) void mgemm_kernel(
    const u16* __restrict__ A, int lda,
    const u16* __restrict__ W, int ldw,
    const float* __restrict__ bias,
    u16* __restrict__ C, int ldc, int K,
    const float* __restrict__ a2w, const float* __restrict__ a2b, float* __restrict__ aln)
{
    __shared__ __align__(16) u16 sA[4096];   // [128][32]
    __shared__ __align__(16) u16 sB[4096];   // [128][32]

    const int tid  = threadIdx.x;
    const int lane = tid & 63;
    const int wid  = tid >> 6;
    const int wr   = wid >> 1, wc = wid & 1;
    const int row0 = blockIdx.x << 7, col0 = blockIdx.y << 7;

    const int e0 = tid << 3,          r0s = e0 >> 5, c0s = e0 & 31;
    const int e1 = (256 + tid) << 3,  r1s = e1 >> 5, c1s = e1 & 31;
    const u16* gA0 = A + (size_t)(row0 + r0s)*lda + c0s;
    const u16* gA1 = A + (size_t)(row0 + r1s)*lda + c1s;
    const u16* gB0 = W + (size_t)(col0 + r0s)*ldw + c0s;
    const u16* gB1 = W + (size_t)(col0 + r1s)*ldw + c1s;
    u16* lA0 = sA + (wid << 9);
    u16* lA1 = sA + 2048 + (wid << 9);
    u16* lB0 = sB + (wid << 9);
    u16* lB1 = sB + 2048 + (wid << 9);

    const int la  = lane & 15;
    const int lk  = (lane >> 4) << 3;
    const int hi4 = (lane >> 4) << 2;
    const u16* rA = sA + (((wr << 6) + la) << 5) + lk;
    const u16* rB = sB + (((wc << 6) + la) << 5) + lk;

    f32x4 acc[4][4];
    {
        f32x4 binit[4];
        #pragma unroll
        for (int n=0;n<4;n++){
            float4 b4 = *reinterpret_cast<const float4*>(bias + col0 + (wc<<6) + (n<<4) + hi4);
            binit[n] = (f32x4){b4.x, b4.y, b4.z, b4.w};
        }
        #pragma unroll
        for (int m=0;m<4;m++)
            #pragma unroll
            for (int n=0;n<4;n++) acc[m][n] = binit[n];
    }

    for (int k0 = 0; k0 < K; k0 += 32){
        gload16(gA0 + k0, lA0);
        gload16(gA1 + k0, lA1);
        gload16(gB0 + k0, lB0);
        gload16(gB1 + k0, lB1);
        __syncthreads();
        bf16x8 af[4], bf[4];
        #pragma unroll
        for (int m=0;m<4;m++) af[m] = *reinterpret_cast<const bf16x8*>(rA + (m << 9));
        #pragma unroll
        for (int n=0;n<4;n++) bf[n] = *reinterpret_cast<const bf16x8*>(rB + (n << 9));
        #pragma unroll
        for (int m=0;m<4;m++)
            #pragma unroll
            for (int n=0;n<4;n++)
                acc[m][n] = __builtin_amdgcn_mfma_f32_16x16x32_bf16(bf[n], af[m], acc[m][n], 0, 0, 0);
        __syncthreads();
    }

    if (ACT == 2){
        // fused: alignment[row] = sigmoid( sum_col gelu(val)*a2w[col] + a2b )
        float w4[4][4];
        #pragma unroll
        for (int n=0;n<4;n++){
            float4 t4 = *reinterpret_cast<const float4*>(a2w + (wc<<6) + (n<<4) + hi4);
            w4[n][0]=t4.x; w4[n][1]=t4.y; w4[n][2]=t4.z; w4[n][3]=t4.w;
        }
        float* red = reinterpret_cast<float*>(sA);   // [128 rows][8 slots], 4KB
        #pragma unroll
        for (int m=0;m<4;m++){
            float p = 0.f;
            #pragma unroll
            for (int n=0;n<4;n++){
                f32x4 v = acc[m][n];
                p += gelu_f(v[0])*w4[n][0] + gelu_f(v[1])*w4[n][1]
                   + gelu_f(v[2])*w4[n][2] + gelu_f(v[3])*w4[n][3];
            }
            red[(((wr<<6) + (m<<4) + la) << 3) + (wc<<2) + (lane>>4)] = p;
        }
        __syncthreads();
        if (tid < 128){
            float s = 0.f;
            #pragma unroll
            for (int k2=0;k2<8;k2++) s += red[(tid<<3)+k2];
            aln[row0 + tid] = 1.0f/(1.0f + __expf(-(s + a2b[0])));
        }
        return;
    }

    #pragma unroll
    for (int m=0;m<4;m++){
        const int grow = row0 + (wr << 6) + (m << 4) + la;
        u16* crow = C + (size_t)grow*ldc + col0 + (wc << 6) + hi4;
        #pragma unroll
        for (int n=0;n<4;n++){
            f32x4 v = acc[m][n];
            float x0=v[0], x1=v[1], x2=v[2], x3=v[3];
            if (ACT == 1){ x0=gelu_f(x0); x1=gelu_f(x1); x2=gelu_f(x2); x3=gelu_f(x3); }
            ushort4 o; o.x=f2bf(x0); o.y=f2bf(x1); o.z=f2bf(x2); o.w=f2bf(x3);
            *reinterpret_cast<ushort4*>(crow + (n << 4)) = o;
        }
    }
}

// ---------------- 256x256 MFMA GEMM, BK=64, 2-buf, 4 phases/tile, no setprio (r14 engine) ----------------
template<int ACT>
__global__ __launch_bounds__(512) void gemm256p_kernel(
    const u16* __restrict__ A, int lda,
    const u16* __restrict__ W, int ldw,
    const float* __restrict__ bias,
    u16* __restrict__ C, int ldc, int K)
{
    __shared__ __align__(16) u16 sT[65536];   // 128 KiB

    const int tid  = threadIdx.x;
    const int lane = tid & 63;
    const int wid  = tid >> 6;            // 0..7
    const int wr   = wid >> 2;            // 0..1
    const int wc   = wid & 3;             // 0..3
    const int row0 = blockIdx.x << 8, col0 = blockIdx.y << 8;

    const int la = lane & 15;
    const int hi = lane >> 4;

    f32x4 acc[8][4];
    {
        f32x4 binit[4];
        #pragma unroll
        for (int n=0;n<4;n++){
            float4 b4 = *reinterpret_cast<const float4*>(bias + col0 + (wc<<6) + (n<<4) + (hi<<2));
            binit[n] = (f32x4){b4.x, b4.y, b4.z, b4.w};
        }
        #pragma unroll
        for (int m=0;m<8;m++)
            #pragma unroll
            for (int n=0;n<4;n++) acc[m][n] = binit[n];
    }

    const int rs = (wid << 4) + (lane >> 3);
    const int cs = ((lane & 7) ^ ((lane >> 3) & 7)) << 3;
    const u16* gA0 = A + (size_t)(row0 + rs)*lda + cs;
    const u16* gA1 = gA0 + (size_t)128*lda;
    const u16* gB0 = W + (size_t)(col0 + rs)*ldw + cs;
    const u16* gB1 = gB0 + (size_t)128*ldw;
    const int ldsw = (wid << 4) * 64;

    const int cph0 = (hi ^ (la & 7)) << 3;
    const u16* rAbase = sT + ((wr << 7) + la)*64;
    const u16* rBbase = sT + 16384 + ((wc << 6) + la)*64;

    const int NT = K >> 6;

    gload16(gB0, sT + 16384 + ldsw);          gload16(gB0 + 8*(size_t)ldw, sT + 16384 + ldsw + 512);
    gload16(gB1, sT + 24576 + ldsw);          gload16(gB1 + 8*(size_t)ldw, sT + 24576 + ldsw + 512);
    gload16(gA0, sT + ldsw);                  gload16(gA0 + 8*(size_t)lda, sT + ldsw + 512);
    gload16(gA1, sT + 8192 + ldsw);           gload16(gA1 + 8*(size_t)lda, sT + 8192 + ldsw + 512);

#define STG(GP, LD, DOFF) \
        gload16(GP + kb, sT + bn + (DOFF) + ldsw); \
        gload16(GP + kb + 8*(size_t)(LD), sT + bn + (DOFF) + ldsw + 512);

#define DSRA(MH, CO) { \
        const u16* rA_ = rAbase + b + ((MH) << 12) + (CO); \
        af[0] = *reinterpret_cast<const bf16x8*>(rA_); \
        af[1] = *reinterpret_cast<const bf16x8*>(rA_ + 1024); \
        af[2] = *reinterpret_cast<const bf16x8*>(rA_ + 2048); \
        af[3] = *reinterpret_cast<const bf16x8*>(rA_ + 3072); }

#define DSRB(CO) { \
        const u16* rB_ = rBbase + b + (CO); \
        bf[0] = *reinterpret_cast<const bf16x8*>(rB_); \
        bf[1] = *reinterpret_cast<const bf16x8*>(rB_ + 1024); \
        bf[2] = *reinterpret_cast<const bf16x8*>(rB_ + 2048); \
        bf[3] = *reinterpret_cast<const bf16x8*>(rB_ + 3072); }

#define MFMA16(MB) { \
        _Pragma("unroll") \
        for (int m=0;m<4;m++){ \
            _Pragma("unroll") \
            for (int n=0;n<4;n++) \
                acc[(MB)+m][n] = __builtin_amdgcn_mfma_f32_16x16x32_bf16(bf[n], af[m], acc[(MB)+m][n], 0,0,0); \
        } }

    for (int t = 0; t < NT; ++t){
        const int b  = (t & 1) << 15;
        const int bn = b ^ 32768;
        const bool stg = (t + 1 < NT);
        const int kb = (t + 1) << 6;
        bf16x8 af[4], bf[4];
        const int co0 = cph0;
        const int co1 = cph0 ^ 32;

        asm volatile("s_waitcnt vmcnt(0)" ::: "memory");
        __builtin_amdgcn_s_barrier();
        __builtin_amdgcn_sched_barrier(0);
        DSRB(co0)
        DSRA(0, co0)
        if (stg){ STG(gB0, ldw, 16384) }
        MFMA16(0)
        DSRA(1, co0)
        if (stg){ STG(gB1, ldw, 24576) }
        __builtin_amdgcn_sched_barrier(0);
        __builtin_amdgcn_s_barrier();
        __builtin_amdgcn_sched_barrier(0);
        MFMA16(4)
        DSRB(co1)
        DSRA(0, co1)
        if (stg){ STG(gA0, lda, 0) }
        __builtin_amdgcn_sched_barrier(0);
        __builtin_amdgcn_s_barrier();
        __builtin_amdgcn_sched_barrier(0);
        MFMA16(0)
        DSRA(1, co1)
        if (stg){ STG(gA1, lda, 8192) }
        __builtin_amdgcn_sched_barrier(0);
        __builtin_amdgcn_s_barrier();
        __builtin_amdgcn_sched_barrier(0);
        MFMA16(4)
    }
#undef STG
#undef DSRA
#undef DSRB
#undef MFMA16

    #pragma unroll
    for (int m=0;m<8;m++){
        const int grow = row0 + (wr << 7) + (m << 4) + la;
        u16* crow = C + (size_t)grow*ldc + col0 + (wc << 6) + (hi << 2);
        #pragma unroll
        for (int n=0;n<4;n++){
            f32x4 v = acc[m][n];
            float x0=v[0], x1=v[1], x2=v[2], x3=v[3];
            if (ACT == 1){ x0=gelu_f(x0); x1=gelu_f(x1); x2=gelu_f(x2); x3=gelu_f(x3); }
            ushort4 o; o.x=f2bf(x0); o.y=f2bf(x1); o.z=f2bf(x2); o.w=f2bf(x3);
            *reinterpret_cast<ushort4*>(crow + (n << 4)) = o;
        }
    }
}

// ---------------- FUSED: attention + out_proj + LN+FiLM -> entry (overwrites wcat[b][0]) ----------------
// Block = 16 samples, 256 threads (4 waves). Grid = 2048.
// NO KV LDS STAGING (each K/V byte consumed by exactly one thread -> staging was pure overhead and
// capped occupancy at 2 blocks/CU). LDS now 26 KB (q/ctx + attn + ao) -> ~5 blocks/CU for latency hiding.
__global__ __launch_bounds__(256) void attnop_kernel(
    const u16* __restrict__ q, const u16* __restrict__ kv,
    u16* __restrict__ wcat,
    const u16* __restrict__ opw, const float* __restrict__ opb,
    const float* __restrict__ regime,
    const float* __restrict__ sgw, const float* __restrict__ sgb,
    const float* __restrict__ sbw, const float* __restrict__ sbb,
    const float* __restrict__ g1, const float* __restrict__ b1)
{
    __shared__ __align__(16) u16 sQC[16*264];     // q then ctx, row stride 264
    __shared__ float sAT[256];                    // attn weights (s*16 + h*4 + n)
    __shared__ __align__(16) float sAO[16*264];   // attn_out f32

    const int t  = threadIdx.x;
    const int b0 = blockIdx.x << 4;

    // ---- load q into LDS (4x reuse downstream) ----
    {
        const int row = t >> 4, u = t & 15;
        const u16* qsrc = q + (size_t)(b0 + row)*256 + (u << 4);
        *reinterpret_cast<bf16x8*>(sQC + row*264 + (u<<4))     = *reinterpret_cast<const bf16x8*>(qsrc);
        *reinterpret_cast<bf16x8*>(sQC + row*264 + (u<<4) + 8) = *reinterpret_cast<const bf16x8*>(qsrc + 8);
    }
    __syncthreads();

    // ---- scores + softmax: thread t = (s, h, n); K read DIRECTLY from global (each byte once) ----
    {
        const int s = t >> 4, h = (t >> 2) & 3, n = t & 3;
        const u16* kp = kv + (size_t)(b0 + s)*2048 + n*512 + h*64;
        const u16* qp = sQC + s*264 + h*64;
        float sc = 0.f;
        #pragma unroll
        for (int j=0;j<8;j++){
            bf16x8 kvv = *reinterpret_cast<const bf16x8*>(kp + (j<<3));
            #pragma unroll
            for (int e=0;e<8;e++) sc += bf2f(qp[(j<<3)+e]) * bf2f((u16)kvv[e]);
        }
        sc *= 0.125f;   // 1/sqrt(64)
        float m = fmaxf(sc, __shfl_xor(sc, 1)); m = fmaxf(m, __shfl_xor(m, 2));
        float e = __expf(sc - m);
        float sum = e + __shfl_xor(e, 1); sum += __shfl_xor(sum, 2);
        sAT[t] = e / sum;
    }
    __syncthreads();   // sAT visible; q reads complete (ctx overlay of sQC safe)

    // ---- ctx[s][d]: V read DIRECTLY from global (each byte once); write ctx into sQC ----
    {
        const int s = t >> 4, u = t & 15;
        const int h = u >> 2;                          // d-range u*16..+15 lies in head h
        const float* a = sAT + s*16 + (h<<2);
        const u16* vbase = kv + (size_t)(b0 + s)*2048 + 256 + (u<<4);
        float cx[16];
        #pragma unroll
        for (int j=0;j<16;j++) cx[j] = 0.f;
        #pragma unroll
        for (int n=0;n<4;n++){
            const float an = a[n];
            bf16x8 v0 = *reinterpret_cast<const bf16x8*>(vbase + n*512);
            bf16x8 v1 = *reinterpret_cast<const bf16x8*>(vbase + n*512 + 8);
            #pragma unroll
            for (int e=0;e<8;e++){
                cx[e]   += an * bf2f((u16)v0[e]);
                cx[8+e] += an * bf2f((u16)v1[e]);
            }
        }
        u16* crow = sQC + s*264 + (u<<4);
        #pragma unroll
        for (int g4=0; g4<4; ++g4){
            ushort4 o;
            o.x=f2bf(cx[g4*4+0]); o.y=f2bf(cx[g4*4+1]); o.z=f2bf(cx[g4*4+2]); o.w=f2bf(cx[g4*4+3]);
            *reinterpret_cast<ushort4*>(crow + (g4<<2)) = o;
        }
    }
    __syncthreads();   // ctx visible

    // ---- ao = ctx @ opw^T + opb via MFMA ----
    {
        const int lane = t & 63, wid = t >> 6;
        const int la = lane & 15, hi = lane >> 4;
        f32x4 acc[4];
        #pragma unroll
        for (int n=0;n<4;n++){
            float4 b4 = *reinterpret_cast<const float4*>(opb + (wid<<6) + (n<<4) + (hi<<2));
            acc[n] = (f32x4){b4.x, b4.y, b4.z, b4.w};
        }
        #pragma unroll
        for (int ks=0; ks<8; ++ks){
            bf16x8 af = *reinterpret_cast<const bf16x8*>(sQC + la*264 + (ks<<5) + (hi<<3));
            #pragma unroll
            for (int n=0;n<4;n++){
                bf16x8 wf = *reinterpret_cast<const bf16x8*>(
                    opw + (size_t)((wid<<6) + (n<<4) + la)*256 + (ks<<5) + (hi<<3));
                acc[n] = __builtin_amdgcn_mfma_f32_16x16x32_bf16(wf, af, acc[n], 0, 0, 0);
            }
        }
        #pragma unroll
        for (int n=0;n<4;n++){
            float4 st = {acc[n][0], acc[n][1], acc[n][2], acc[n][3]};
            *reinterpret_cast<float4*>(sAO + la*264 + (wid<<6) + (n<<4) + (hi<<2)) = st;
        }
    }
    __syncthreads();

    // ---- entry = FiLM(LN(query + ao)) -> wcat row 0 ----
    {
        const int s = t >> 4, u = t & 15;
        u16* qrow = wcat + (size_t)(b0 + s)*1024;
        float xv[16], sum = 0.f, sq = 0.f;
        #pragma unroll
        for (int j=0;j<16;j++){
            const int d = u + (j << 4);
            float x = sAO[s*264 + d] + bf2f(qrow[d]);
            xv[j] = x; sum += x; sq += x*x;
        }
        #pragma unroll
        for (int o=1;o<16;o<<=1){ sum += __shfl_xor(sum, o); sq += __shfl_xor(sq, o); }
        float mu   = sum * (1.0f/256.0f);
        float var  = sq  * (1.0f/256.0f) - mu*mu;
        float rstd = rsqrtf(var + 1e-5f);
        const float r0 = regime[(b0+s)*4+0], r1 = regime[(b0+s)*4+1];
        const float r2 = regime[(b0+s)*4+2], r3 = regime[(b0+s)*4+3];
        #pragma unroll
        for (int j=0;j<16;j++){
            const int d = u + (j << 4);
            float gam = r0*sgw[d*4+0] + r1*sgw[d*4+1] + r2*sgw[d*4+2] + r3*sgw[d*4+3] + sgb[d];
            float bet = r0*sbw[d*4+0] + r1*sbw[d*4+1] + r2*sbw[d*4+2] + r3*sbw[d*4+3] + sbb[d];
            float e = ((xv[j]-mu)*rstd*g1[d] + b1[d])*(1.0f+gam) + bet;
            qrow[d] = f2bf(e);
        }
    }
}

// ---------------- fused = LN(t1) -> f32 out ----------------
__global__ __launch_bounds__(256) void ln2_kernel(
    const u16* __restrict__ t1, const float* __restrict__ g, const float* __restrict__ bt,
    float* __restrict__ out)
{
    const int b = blockIdx.x, t = threadIdx.x;
    float x0 = bf2f(t1[(size_t)b*512 + t]);
    float x1 = bf2f(t1[(size_t)b*512 + 256 + t]);
    float s = x0+x1, q = x0*x0 + x1*x1;
    #pragma unroll
    for (int o=32;o;o>>=1){ s += __shfl_xor(s,o); q += __shfl_xor(q,o); }
    __shared__ float rs[4], rq[4];
    if ((t&63)==0){ rs[t>>6]=s; rq[t>>6]=q; }
    __syncthreads();
    s = rs[0]+rs[1]+rs[2]+rs[3];
    q = rq[0]+rq[1]+rq[2]+rq[3];
    float mu  = s*(1.0f/512.0f);
    float var = q*(1.0f/512.0f) - mu*mu;
    float rstd = rsqrtf(var + 1e-5f);
    out[(size_t)b*512 + t]       = (x0-mu)*rstd*g[t]     + bt[t];
    out[(size_t)b*512 + 256 + t] = (x1-mu)*rstd*g[256+t] + bt[256+t];
}

extern "C" void kernel_launch(void* const* d_in, const int* in_sizes, int n_in,
                              void* d_out, int out_size, void* d_ws, size_t ws_size,
                              hipStream_t stream) {
    const float* w0   = (const float*)d_in[0];
    const float* w1   = (const float*)d_in[1];
    const float* w2   = (const float*)d_in[2];
    const float* w3   = (const float*)d_in[3];
    const float* regime = (const float*)d_in[4];
    const float* tfw  = (const float*)d_in[5];
    const float* in_proj_w = (const float*)d_in[6];
    const float* in_proj_b = (const float*)d_in[7];
    const float* out_proj_w = (const float*)d_in[8];
    const float* out_proj_b = (const float*)d_in[9];
    const float* ln1_g = (const float*)d_in[10];
    const float* ln1_b = (const float*)d_in[11];
    const float* sg_w = (const float*)d_in[12];
    const float* sg_b = (const float*)d_in[13];
    const float* sb_w = (const float*)d_in[14];
    const float* sb_b = (const float*)d_in[15];
    const float* f1_w = (const float*)d_in[16];
    const float* f1_b = (const float*)d_in[17];
    const float* f2_w = (const float*)d_in[18];
    const float* f2_b = (const float*)d_in[19];
    const float* ln2_g = (const float*)d_in[20];
    const float* ln2_b = (const float*)d_in[21];
    const float* a1_w = (const float*)d_in[22];
    const float* a1_b = (const float*)d_in[23];
    const float* a2_w = (const float*)d_in[24];
    const float* a2_b = (const float*)d_in[25];

    char* ws = (char*)d_ws;
    u16* wcat  = (u16*)(ws);
    u16* qbuf  = (u16*)(ws + 67108864ull);     // 64..80Mi
    u16* kvbuf = (u16*)(ws + 83886080ull);     // 80..208Mi
    u16* hbuf  = kvbuf;                        // 80..144Mi after attnop
    u16* t1buf = (u16*)(ws + 150994944ull);    // 144..176Mi
    u16* wb    = (u16*)(ws + 218103808ull);
    u16* ipw = wb;                // 196608 elems
    u16* opw = wb + 196608;       // 65536
    u16* f1w = wb + 262144;       // 1048576
    u16* f2w = wb + 1310720;      // 524288
    u16* a1w = wb + 1835008;      // 131072

    float* out_fused = (float*)d_out;
    float* out_align = (float*)d_out + (size_t)NB*512;

    // 1. prep + all weight conversions
    prepconv_kernel<<<10112, 256, 0, stream>>>(w0,w1,w2,w3,tfw,wcat,
        in_proj_w,ipw, out_proj_w,opw, f1_w,f1w, f2_w,f2w, a1_w,a1w);
    // 2. q = query @ wq^T + bq
    mgemm_kernel<0><<<dim3(256, 2), 256, 0, stream>>>(wcat, 1024, ipw, 256, in_proj_b, qbuf, 256, 256, nullptr, nullptr, nullptr);
    // 3. kv = weighted @ [wk;wv]^T + b
    gemm256p_kernel<0><<<dim3(512, 2), 512, 0, stream>>>(wcat, 256, ipw+65536, 256, in_proj_b+256, kvbuf, 512, 256);
    // 4. FUSED attention + out_proj + LN+FiLM -> wcat entry rows
    attnop_kernel<<<2048, 256, 0, stream>>>(qbuf, kvbuf, wcat, opw, out_proj_b,
        regime, sg_w, sg_b, sb_w, sb_b, ln1_g, ln1_b);
    // 5. h = gelu(cat @ f1^T + b) -> hbuf
    gemm256p_kernel<1><<<dim3(128, 4), 512, 0, stream>>>(wcat, 1024, f1w, 1024, f1_b, hbuf, 1024, 1024);
    // 6. alignment = sigmoid(gelu(cat @ a1^T + b) @ a2^T + b)  — wcat L2/L3-hot after f1
    mgemm_kernel<2><<<dim3(256, 1), 256, 0, stream>>>(wcat, 1024, a1w, 1024, a1_b, qbuf, 128, 1024, a2_w, a2_b, out_align);
    // 7. t1 = h @ f2^T + b
    gemm256p_kernel<0><<<dim3(128, 2), 512, 0, stream>>>(hbuf, 1024, f2w, 1024, f2_b, t1buf, 512, 1024);
    // 8. fused = LN(t1) -> out
    ln2_kernel<<<NB, 256, 0, stream>>>(t1buf, ln2_g, ln2_b, out_fused);
}

// Round 21
// 340.652 us; speedup vs baseline: 1.1624x; 1.1624x over previous
//
#include <hip/hip_runtime.h>
#include <math.h>

#define NB 32768   // batch
// D=256, N=4, OUT=512, H=4, DH=64

typedef unsigned short u16;
typedef __attribute__((ext_vector_type(4))) float f32x4;
typedef __attribute__((ext_vector_type(8))) short bf16x8;

__device__ __forceinline__ float bf2f(u16 u){ return __uint_as_float(((unsigned int)u)<<16); }
__device__ __forceinline__ u16 f2bf(float f){
    unsigned int x = __float_as_uint(f);
    x += 0x7fffu + ((x>>16)&1u);   // round-to-nearest-even
    return (u16)(x>>16);
}
// gelu exact-erf via A&S 7.1.26 (|eps|<=1.5e-7), branchless: rcp + exp + 5 fma
__device__ __forceinline__ float gelu_f(float x){
    float z = fabsf(x) * 0.70710678118654752f;
    float t = __builtin_amdgcn_rcpf(1.0f + 0.3275911f*z);
    float p = t*(0.254829592f + t*(-0.284496736f + t*(1.421413741f + t*(-1.453152027f + t*1.061405429f))));
    float e = __expf(-z*z);
    float erf_abs = 1.0f - p*e;
    float erfv = copysignf(erf_abs, x);
    return 0.5f*x*(1.0f + erfv);
}

__device__ __forceinline__ void gload16(const void* g, void* l){
    __builtin_amdgcn_global_load_lds(
        (const __attribute__((address_space(1))) unsigned int*)g,
        (__attribute__((address_space(3))) unsigned int*)l, 16, 0, 0);
}

// ---------------- prep (scale w0..w3 by softmax(tfw)) + all weight fp32->bf16 conversions ----------------
__global__ __launch_bounds__(256) void prepconv_kernel(
    const float* __restrict__ w0, const float* __restrict__ w1,
    const float* __restrict__ w2, const float* __restrict__ w3,
    const float* __restrict__ tfw, u16* __restrict__ wcat,
    const float* __restrict__ ipw_s, u16* __restrict__ ipw_d,
    const float* __restrict__ op_s,  u16* __restrict__ op_d,
    const float* __restrict__ f1_s,  u16* __restrict__ f1_d,
    const float* __restrict__ f2_s,  u16* __restrict__ f2_d,
    const float* __restrict__ a1_s,  u16* __restrict__ a1_d)
{
    const int blk = blockIdx.x, tid = threadIdx.x;
    if (blk < 8192){
        float t0=tfw[0], t1=tfw[1], t2=tfw[2], t3=tfw[3];
        float m = fmaxf(fmaxf(t0,t1), fmaxf(t2,t3));
        float e0=expf(t0-m), e1=expf(t1-m), e2=expf(t2-m), e3=expf(t3-m);
        float inv = 1.0f/(e0+e1+e2+e3);
        float s0=e0*inv, s1=e1*inv, s2=e2*inv, s3=e3*inv;

        int idx = blk*256 + tid;
        int b  = idx >> 6;
        int d4 = (idx & 63) << 2;
        size_t src = (size_t)b*256 + d4;
        float4 a0 = *reinterpret_cast<const float4*>(w0 + src);
        float4 a1 = *reinterpret_cast<const float4*>(w1 + src);
        float4 a2 = *reinterpret_cast<const float4*>(w2 + src);
        float4 a3 = *reinterpret_cast<const float4*>(w3 + src);
        size_t dst = (size_t)b*1024 + d4;
        ushort4 o;
        o.x=f2bf(a0.x*s0); o.y=f2bf(a0.y*s0); o.z=f2bf(a0.z*s0); o.w=f2bf(a0.w*s0);
        *reinterpret_cast<ushort4*>(wcat + dst) = o;
        o.x=f2bf(a1.x*s1); o.y=f2bf(a1.y*s1); o.z=f2bf(a1.z*s1); o.w=f2bf(a1.w*s1);
        *reinterpret_cast<ushort4*>(wcat + dst + 256) = o;
        o.x=f2bf(a2.x*s2); o.y=f2bf(a2.y*s2); o.z=f2bf(a2.z*s2); o.w=f2bf(a2.w*s2);
        *reinterpret_cast<ushort4*>(wcat + dst + 512) = o;
        o.x=f2bf(a3.x*s3); o.y=f2bf(a3.y*s3); o.z=f2bf(a3.z*s3); o.w=f2bf(a3.w*s3);
        *reinterpret_cast<ushort4*>(wcat + dst + 768) = o;
    } else {
        int i = (blk - 8192)*256 + tid;   // float4 index across all weights
        const float* s; u16* d; int off;
        if      (i < 49152)  { s=ipw_s; d=ipw_d; off=i; }
        else if (i < 65536)  { s=op_s;  d=op_d;  off=i-49152; }
        else if (i < 327680) { s=f1_s;  d=f1_d;  off=i-65536; }
        else if (i < 458752) { s=f2_s;  d=f2_d;  off=i-327680; }
        else                 { s=a1_s;  d=a1_d;  off=i-458752; }
        float4 v = reinterpret_cast<const float4*>(s)[off];
        ushort4 o; o.x=f2bf(v.x); o.y=f2bf(v.y); o.z=f2bf(v.z); o.w=f2bf(v.w);
        reinterpret_cast<ushort4*>(d)[off] = o;
    }
}

// ---------------- 128x128 MFMA GEMM. ACT: 0 none, 1 gelu, 2 gelu + fused a2 row-dot ----------------
template<int ACT>
__global__ __launch_bounds__(256) void mgemm_kernel(
    const u16* __restrict__ A, int lda,
    const u16* __restrict__ W, int ldw,
    const float* __restrict__ bias,
    u16* __restrict__ C, int ldc, int K,
    const float* __restrict__ a2w, const float* __restrict__ a2b, float* __restrict__ aln)
{
    __shared__ __align__(16) u16 sA[4096];   // [128][32]
    __shared__ __align__(16) u16 sB[4096];   // [128][32]

    const int tid  = threadIdx.x;
    const int lane = tid & 63;
    const int wid  = tid >> 6;
    const int wr   = wid >> 1, wc = wid & 1;
    const int row0 = blockIdx.x << 7, col0 = blockIdx.y << 7;

    const int e0 = tid << 3,          r0s = e0 >> 5, c0s = e0 & 31;
    const int e1 = (256 + tid) << 3,  r1s = e1 >> 5, c1s = e1 & 31;
    const u16* gA0 = A + (size_t)(row0 + r0s)*lda + c0s;
    const u16* gA1 = A + (size_t)(row0 + r1s)*lda + c1s;
    const u16* gB0 = W + (size_t)(col0 + r0s)*ldw + c0s;
    const u16* gB1 = W + (size_t)(col0 + r1s)*ldw + c1s;
    u16* lA0 = sA + (wid << 9);
    u16* lA1 = sA + 2048 + (wid << 9);
    u16* lB0 = sB + (wid << 9);
    u16* lB1 = sB + 2048 + (wid << 9);

    const int la  = lane & 15;
    const int lk  = (lane >> 4) << 3;
    const int hi4 = (lane >> 4) << 2;
    const u16* rA = sA + (((wr << 6) + la) << 5) + lk;
    const u16* rB = sB + (((wc << 6) + la) << 5) + lk;

    f32x4 acc[4][4];
    {
        f32x4 binit[4];
        #pragma unroll
        for (int n=0;n<4;n++){
            float4 b4 = *reinterpret_cast<const float4*>(bias + col0 + (wc<<6) + (n<<4) + hi4);
            binit[n] = (f32x4){b4.x, b4.y, b4.z, b4.w};
        }
        #pragma unroll
        for (int m=0;m<4;m++)
            #pragma unroll
            for (int n=0;n<4;n++) acc[m][n] = binit[n];
    }

    for (int k0 = 0; k0 < K; k0 += 32){
        gload16(gA0 + k0, lA0);
        gload16(gA1 + k0, lA1);
        gload16(gB0 + k0, lB0);
        gload16(gB1 + k0, lB1);
        __syncthreads();
        bf16x8 af[4], bf[4];
        #pragma unroll
        for (int m=0;m<4;m++) af[m] = *reinterpret_cast<const bf16x8*>(rA + (m << 9));
        #pragma unroll
        for (int n=0;n<4;n++) bf[n] = *reinterpret_cast<const bf16x8*>(rB + (n << 9));
        #pragma unroll
        for (int m=0;m<4;m++)
            #pragma unroll
            for (int n=0;n<4;n++)
                acc[m][n] = __builtin_amdgcn_mfma_f32_16x16x32_bf16(bf[n], af[m], acc[m][n], 0, 0, 0);
        __syncthreads();
    }

    if (ACT == 2){
        // fused: alignment[row] = sigmoid( sum_col gelu(val)*a2w[col] + a2b )
        float w4[4][4];
        #pragma unroll
        for (int n=0;n<4;n++){
            float4 t4 = *reinterpret_cast<const float4*>(a2w + (wc<<6) + (n<<4) + hi4);
            w4[n][0]=t4.x; w4[n][1]=t4.y; w4[n][2]=t4.z; w4[n][3]=t4.w;
        }
        float* red = reinterpret_cast<float*>(sA);   // [128 rows][8 slots], 4KB
        #pragma unroll
        for (int m=0;m<4;m++){
            float p = 0.f;
            #pragma unroll
            for (int n=0;n<4;n++){
                f32x4 v = acc[m][n];
                p += gelu_f(v[0])*w4[n][0] + gelu_f(v[1])*w4[n][1]
                   + gelu_f(v[2])*w4[n][2] + gelu_f(v[3])*w4[n][3];
            }
            red[(((wr<<6) + (m<<4) + la) << 3) + (wc<<2) + (lane>>4)] = p;
        }
        __syncthreads();
        if (tid < 128){
            float s = 0.f;
            #pragma unroll
            for (int k2=0;k2<8;k2++) s += red[(tid<<3)+k2];
            aln[row0 + tid] = 1.0f/(1.0f + __expf(-(s + a2b[0])));
        }
        return;
    }

    #pragma unroll
    for (int m=0;m<4;m++){
        const int grow = row0 + (wr << 6) + (m << 4) + la;
        u16* crow = C + (size_t)grow*ldc + col0 + (wc << 6) + hi4;
        #pragma unroll
        for (int n=0;n<4;n++){
            f32x4 v = acc[m][n];
            float x0=v[0], x1=v[1], x2=v[2], x3=v[3];
            if (ACT == 1){ x0=gelu_f(x0); x1=gelu_f(x1); x2=gelu_f(x2); x3=gelu_f(x3); }
            ushort4 o; o.x=f2bf(x0); o.y=f2bf(x1); o.z=f2bf(x2); o.w=f2bf(x3);
            *reinterpret_cast<ushort4*>(crow + (n << 4)) = o;
        }
    }
}

// ---------------- 256x256 MFMA GEMM, BK=64, 2-buf, 4 phases/tile, no setprio (r14 engine) ----------------
template<int ACT>
__global__ __launch_bounds__(512) void gemm256p_kernel(
    const u16* __restrict__ A, int lda,
    const u16* __restrict__ W, int ldw,
    const float* __restrict__ bias,
    u16* __restrict__ C, int ldc, int K)
{
    __shared__ __align__(16) u16 sT[65536];   // 128 KiB

    const int tid  = threadIdx.x;
    const int lane = tid & 63;
    const int wid  = tid >> 6;            // 0..7
    const int wr   = wid >> 2;            // 0..1
    const int wc   = wid & 3;             // 0..3
    const int row0 = blockIdx.x << 8, col0 = blockIdx.y << 8;

    const int la = lane & 15;
    const int hi = lane >> 4;

    f32x4 acc[8][4];
    {
        f32x4 binit[4];
        #pragma unroll
        for (int n=0;n<4;n++){
            float4 b4 = *reinterpret_cast<const float4*>(bias + col0 + (wc<<6) + (n<<4) + (hi<<2));
            binit[n] = (f32x4){b4.x, b4.y, b4.z, b4.w};
        }
        #pragma unroll
        for (int m=0;m<8;m++)
            #pragma unroll
            for (int n=0;n<4;n++) acc[m][n] = binit[n];
    }

    const int rs = (wid << 4) + (lane >> 3);
    const int cs = ((lane & 7) ^ ((lane >> 3) & 7)) << 3;
    const u16* gA0 = A + (size_t)(row0 + rs)*lda + cs;
    const u16* gA1 = gA0 + (size_t)128*lda;
    const u16* gB0 = W + (size_t)(col0 + rs)*ldw + cs;
    const u16* gB1 = gB0 + (size_t)128*ldw;
    const int ldsw = (wid << 4) * 64;

    const int cph0 = (hi ^ (la & 7)) << 3;
    const u16* rAbase = sT + ((wr << 7) + la)*64;
    const u16* rBbase = sT + 16384 + ((wc << 6) + la)*64;

    const int NT = K >> 6;

    gload16(gB0, sT + 16384 + ldsw);          gload16(gB0 + 8*(size_t)ldw, sT + 16384 + ldsw + 512);
    gload16(gB1, sT + 24576 + ldsw);          gload16(gB1 + 8*(size_t)ldw, sT + 24576 + ldsw + 512);
    gload16(gA0, sT + ldsw);                  gload16(gA0 + 8*(size_t)lda, sT + ldsw + 512);
    gload16(gA1, sT + 8192 + ldsw);           gload16(gA1 + 8*(size_t)lda, sT + 8192 + ldsw + 512);

#define STG(GP, LD, DOFF) \
        gload16(GP + kb, sT + bn + (DOFF) + ldsw); \
        gload16(GP + kb + 8*(size_t)(LD), sT + bn + (DOFF) + ldsw + 512);

#define DSRA(MH, CO) { \
        const u16* rA_ = rAbase + b + ((MH) << 12) + (CO); \
        af[0] = *reinterpret_cast<const bf16x8*>(rA_); \
        af[1] = *reinterpret_cast<const bf16x8*>(rA_ + 1024); \
        af[2] = *reinterpret_cast<const bf16x8*>(rA_ + 2048); \
        af[3] = *reinterpret_cast<const bf16x8*>(rA_ + 3072); }

#define DSRB(CO) { \
        const u16* rB_ = rBbase + b + (CO); \
        bf[0] = *reinterpret_cast<const bf16x8*>(rB_); \
        bf[1] = *reinterpret_cast<const bf16x8*>(rB_ + 1024); \
        bf[2] = *reinterpret_cast<const bf16x8*>(rB_ + 2048); \
        bf[3] = *reinterpret_cast<const bf16x8*>(rB_ + 3072); }

#define MFMA16(MB) { \
        _Pragma("unroll") \
        for (int m=0;m<4;m++){ \
            _Pragma("unroll") \
            for (int n=0;n<4;n++) \
                acc[(MB)+m][n] = __builtin_amdgcn_mfma_f32_16x16x32_bf16(bf[n], af[m], acc[(MB)+m][n], 0,0,0); \
        } }

    for (int t = 0; t < NT; ++t){
        const int b  = (t & 1) << 15;
        const int bn = b ^ 32768;
        const bool stg = (t + 1 < NT);
        const int kb = (t + 1) << 6;
        bf16x8 af[4], bf[4];
        const int co0 = cph0;
        const int co1 = cph0 ^ 32;

        asm volatile("s_waitcnt vmcnt(0)" ::: "memory");
        __builtin_amdgcn_s_barrier();
        __builtin_amdgcn_sched_barrier(0);
        DSRB(co0)
        DSRA(0, co0)
        if (stg){ STG(gB0, ldw, 16384) }
        MFMA16(0)
        DSRA(1, co0)
        if (stg){ STG(gB1, ldw, 24576) }
        __builtin_amdgcn_sched_barrier(0);
        __builtin_amdgcn_s_barrier();
        __builtin_amdgcn_sched_barrier(0);
        MFMA16(4)
        DSRB(co1)
        DSRA(0, co1)
        if (stg){ STG(gA0, lda, 0) }
        __builtin_amdgcn_sched_barrier(0);
        __builtin_amdgcn_s_barrier();
        __builtin_amdgcn_sched_barrier(0);
        MFMA16(0)
        DSRA(1, co1)
        if (stg){ STG(gA1, lda, 8192) }
        __builtin_amdgcn_sched_barrier(0);
        __builtin_amdgcn_s_barrier();
        __builtin_amdgcn_sched_barrier(0);
        MFMA16(4)
    }
#undef STG
#undef DSRA
#undef DSRB
#undef MFMA16

    #pragma unroll
    for (int m=0;m<8;m++){
        const int grow = row0 + (wr << 7) + (m << 4) + la;
        u16* crow = C + (size_t)grow*ldc + col0 + (wc << 6) + (hi << 2);
        #pragma unroll
        for (int n=0;n<4;n++){
            f32x4 v = acc[m][n];
            float x0=v[0], x1=v[1], x2=v[2], x3=v[3];
            if (ACT == 1){ x0=gelu_f(x0); x1=gelu_f(x1); x2=gelu_f(x2); x3=gelu_f(x3); }
            ushort4 o; o.x=f2bf(x0); o.y=f2bf(x1); o.z=f2bf(x2); o.w=f2bf(x3);
            *reinterpret_cast<ushort4*>(crow + (n << 4)) = o;
        }
    }
}

// ---------------- FUSED: attention + out_proj + LN+FiLM -> entry (overwrites wcat[b][0]) ----------------
// Block = 16 samples, 256 threads (4 waves). Grid = 2048.
// K STAGED into [256 rows][66] (row = s*16+h*4+n; coalesced 128B-segment loads; 2-way/free reads);
// V DIRECT from global (512B-segment pattern, coalesced, zero reuse). q staged [s*4+h][66].
// Overlays after score barrier: ctx = first half of sK region; sAO f32 = second half. LDS ~43KB -> 3 blocks/CU.
__global__ __launch_bounds__(256) void attnop_kernel(
    const u16* __restrict__ q, const u16* __restrict__ kv,
    u16* __restrict__ wcat,
    const u16* __restrict__ opw, const float* __restrict__ opb,
    const float* __restrict__ regime,
    const float* __restrict__ sgw, const float* __restrict__ sgb,
    const float* __restrict__ sbw, const float* __restrict__ sbb,
    const float* __restrict__ g1, const float* __restrict__ b1)
{
    __shared__ __align__(16) u16 sK[16896];       // 256 rows x 66 (33792 B)
    __shared__ __align__(16) u16 sQ[4224];        // 64 rows (s*4+h) x 66
    __shared__ float sAT[256];                    // attn weights (s*16 + h*4 + n)

    const int t  = threadIdx.x;
    const int b0 = blockIdx.x << 4;

    // ---- stage q ([s*4+h][66]) + K ([s*16+h*4+n][66], all 256 rows) ----
    {
        const int row = t >> 4, u = t & 15;
        const u16* qsrc = q + (size_t)(b0 + row)*256 + (u << 4);
        u16* qdst = sQ + ((row << 2) + (u >> 2))*66 + ((u & 3) << 4);
        *reinterpret_cast<bf16x8*>(qdst)     = *reinterpret_cast<const bf16x8*>(qsrc);
        *reinterpret_cast<bf16x8*>(qdst + 8) = *reinterpret_cast<const bf16x8*>(qsrc + 8);

        #pragma unroll
        for (int r=0;r<8;r++){
            const int idx  = (r << 8) + t;            // 0..2047
            const int rk   = idx >> 3;                // K row 0..255 = s*16+h*4+n
            const int slot = idx & 7;
            const int s = rk >> 4, h = (rk >> 2) & 3, n = rk & 3;
            const u16* ksrc = kv + (size_t)(b0 + s)*2048 + n*512 + h*64 + (slot << 3);
            *reinterpret_cast<bf16x8*>(sK + rk*66 + (slot << 3)) = *reinterpret_cast<const bf16x8*>(ksrc);
        }
    }
    __syncthreads();

    // ---- scores + softmax: thread t = (s, h, n); K row = t, q row = s*4+h; shfl over n ----
    {
        const u16* kp = sK + t*66;
        const u16* qp = sQ + (((t >> 4) << 2) + ((t >> 2) & 3))*66;
        float sc = 0.f;
        #pragma unroll
        for (int j=0;j<8;j++){
            bf16x8 kvv = *reinterpret_cast<const bf16x8*>(kp + (j<<3));
            bf16x8 qv  = *reinterpret_cast<const bf16x8*>(qp + (j<<3));
            #pragma unroll
            for (int e=0;e<8;e++) sc += bf2f((u16)qv[e]) * bf2f((u16)kvv[e]);
        }
        sc *= 0.125f;   // 1/sqrt(64)
        float m = fmaxf(sc, __shfl_xor(sc, 1)); m = fmaxf(m, __shfl_xor(m, 2));
        float e = __expf(sc - m);
        float sum = e + __shfl_xor(e, 1); sum += __shfl_xor(sum, 2);
        sAT[t] = e / sum;
    }
    __syncthreads();   // sAT visible; sK reads complete (overlays safe)

    // ---- ctx[s][d]: V DIRECT from global; ctx -> first half of sK region ([16][264]) ----
    u16* sCTX = sK;                                       // u16 [0 .. 4224)
    float* sAO = reinterpret_cast<float*>(sK + 8448);     // f32 [16][264] in u16 range [8448,16896)
    {
        const int s = t >> 4, u = t & 15;
        const int h = u >> 2;                          // d-range u*16..+15 lies in head h
        const float* a = sAT + s*16 + (h<<2);
        const u16* vbase = kv + (size_t)(b0 + s)*2048 + 256 + (u<<4);
        float cx[16];
        #pragma unroll
        for (int j=0;j<16;j++) cx[j] = 0.f;
        #pragma unroll
        for (int n=0;n<4;n++){
            const float an = a[n];
            bf16x8 v0 = *reinterpret_cast<const bf16x8*>(vbase + n*512);
            bf16x8 v1 = *reinterpret_cast<const bf16x8*>(vbase + n*512 + 8);
            #pragma unroll
            for (int e=0;e<8;e++){
                cx[e]   += an * bf2f((u16)v0[e]);
                cx[8+e] += an * bf2f((u16)v1[e]);
            }
        }
        u16* crow = sCTX + s*264 + (u<<4);
        #pragma unroll
        for (int g4=0; g4<4; ++g4){
            ushort4 o;
            o.x=f2bf(cx[g4*4+0]); o.y=f2bf(cx[g4*4+1]); o.z=f2bf(cx[g4*4+2]); o.w=f2bf(cx[g4*4+3]);
            *reinterpret_cast<ushort4*>(crow + (g4<<2)) = o;
        }
    }
    __syncthreads();   // ctx visible

    // ---- ao = ctx @ opw^T + opb via MFMA ----
    {
        const int lane = t & 63, wid = t >> 6;
        const int la = lane & 15, hi = lane >> 4;
        f32x4 acc[4];
        #pragma unroll
        for (int n=0;n<4;n++){
            float4 b4 = *reinterpret_cast<const float4*>(opb + (wid<<6) + (n<<4) + (hi<<2));
            acc[n] = (f32x4){b4.x, b4.y, b4.z, b4.w};
        }
        #pragma unroll
        for (int ks=0; ks<8; ++ks){
            bf16x8 af = *reinterpret_cast<const bf16x8*>(sCTX + la*264 + (ks<<5) + (hi<<3));
            #pragma unroll
            for (int n=0;n<4;n++){
                bf16x8 wf = *reinterpret_cast<const bf16x8*>(
                    opw + (size_t)((wid<<6) + (n<<4) + la)*256 + (ks<<5) + (hi<<3));
                acc[n] = __builtin_amdgcn_mfma_f32_16x16x32_bf16(wf, af, acc[n], 0, 0, 0);
            }
        }
        #pragma unroll
        for (int n=0;n<4;n++){
            float4 st = {acc[n][0], acc[n][1], acc[n][2], acc[n][3]};
            *reinterpret_cast<float4*>(sAO + la*264 + (wid<<6) + (n<<4) + (hi<<2)) = st;
        }
    }
    __syncthreads();

    // ---- entry = FiLM(LN(query + ao)) -> wcat row 0 ----
    {
        const int s = t >> 4, u = t & 15;
        u16* qrow = wcat + (size_t)(b0 + s)*1024;
        float xv[16], sum = 0.f, sq = 0.f;
        #pragma unroll
        for (int j=0;j<16;j++){
            const int d = u + (j << 4);
            float x = sAO[s*264 + d] + bf2f(qrow[d]);
            xv[j] = x; sum += x; sq += x*x;
        }
        #pragma unroll
        for (int o=1;o<16;o<<=1){ sum += __shfl_xor(sum, o); sq += __shfl_xor(sq, o); }
        float mu   = sum * (1.0f/256.0f);
        float var  = sq  * (1.0f/256.0f) - mu*mu;
        float rstd = rsqrtf(var + 1e-5f);
        const float r0 = regime[(b0+s)*4+0], r1 = regime[(b0+s)*4+1];
        const float r2 = regime[(b0+s)*4+2], r3 = regime[(b0+s)*4+3];
        #pragma unroll
        for (int j=0;j<16;j++){
            const int d = u + (j << 4);
            float gam = r0*sgw[d*4+0] + r1*sgw[d*4+1] + r2*sgw[d*4+2] + r3*sgw[d*4+3] + sgb[d];
            float bet = r0*sbw[d*4+0] + r1*sbw[d*4+1] + r2*sbw[d*4+2] + r3*sbw[d*4+3] + sbb[d];
            float e = ((xv[j]-mu)*rstd*g1[d] + b1[d])*(1.0f+gam) + bet;
            qrow[d] = f2bf(e);
        }
    }
}

// ---------------- fused = LN(t1) -> f32 out ----------------
__global__ __launch_bounds__(256) void ln2_kernel(
    const u16* __restrict__ t1, const float* __restrict__ g, const float* __restrict__ bt,
    float* __restrict__ out)
{
    const int b = blockIdx.x, t = threadIdx.x;
    float x0 = bf2f(t1[(size_t)b*512 + t]);
    float x1 = bf2f(t1[(size_t)b*512 + 256 + t]);
    float s = x0+x1, q = x0*x0 + x1*x1;
    #pragma unroll
    for (int o=32;o;o>>=1){ s += __shfl_xor(s,o); q += __shfl_xor(q,o); }
    __shared__ float rs[4], rq[4];
    if ((t&63)==0){ rs[t>>6]=s; rq[t>>6]=q; }
    __syncthreads();
    s = rs[0]+rs[1]+rs[2]+rs[3];
    q = rq[0]+rq[1]+rq[2]+rq[3];
    float mu  = s*(1.0f/512.0f);
    float var = q*(1.0f/512.0f) - mu*mu;
    float rstd = rsqrtf(var + 1e-5f);
    out[(size_t)b*512 + t]       = (x0-mu)*rstd*g[t]     + bt[t];
    out[(size_t)b*512 + 256 + t] = (x1-mu)*rstd*g[256+t] + bt[256+t];
}

extern "C" void kernel_launch(void* const* d_in, const int* in_sizes, int n_in,
                              void* d_out, int out_size, void* d_ws, size_t ws_size,
                              hipStream_t stream) {
    const float* w0   = (const float*)d_in[0];
    const float* w1   = (const float*)d_in[1];
    const float* w2   = (const float*)d_in[2];
    const float* w3   = (const float*)d_in[3];
    const float* regime = (const float*)d_in[4];
    const float* tfw  = (const float*)d_in[5];
    const float* in_proj_w = (const float*)d_in[6];
    const float* in_proj_b = (const float*)d_in[7];
    const float* out_proj_w = (const float*)d_in[8];
    const float* out_proj_b = (const float*)d_in[9];
    const float* ln1_g = (const float*)d_in[10];
    const float* ln1_b = (const float*)d_in[11];
    const float* sg_w = (const float*)d_in[12];
    const float* sg_b = (const float*)d_in[13];
    const float* sb_w = (const float*)d_in[14];
    const float* sb_b = (const float*)d_in[15];
    const float* f1_w = (const float*)d_in[16];
    const float* f1_b = (const float*)d_in[17];
    const float* f2_w = (const float*)d_in[18];
    const float* f2_b = (const float*)d_in[19];
    const float* ln2_g = (const float*)d_in[20];
    const float* ln2_b = (const float*)d_in[21];
    const float* a1_w = (const float*)d_in[22];
    const float* a1_b = (const float*)d_in[23];
    const float* a2_w = (const float*)d_in[24];
    const float* a2_b = (const float*)d_in[25];

    char* ws = (char*)d_ws;
    u16* wcat  = (u16*)(ws);
    u16* qbuf  = (u16*)(ws + 67108864ull);     // 64..80Mi
    u16* kvbuf = (u16*)(ws + 83886080ull);     // 80..208Mi
    u16* hbuf  = kvbuf;                        // 80..144Mi after attnop
    u16* t1buf = (u16*)(ws + 150994944ull);    // 144..176Mi
    u16* wb    = (u16*)(ws + 218103808ull);
    u16* ipw = wb;                // 196608 elems
    u16* opw = wb + 196608;       // 65536
    u16* f1w = wb + 262144;       // 1048576
    u16* f2w = wb + 1310720;      // 524288
    u16* a1w = wb + 1835008;      // 131072

    float* out_fused = (float*)d_out;
    float* out_align = (float*)d_out + (size_t)NB*512;

    // 1. prep + all weight conversions
    prepconv_kernel<<<10112, 256, 0, stream>>>(w0,w1,w2,w3,tfw,wcat,
        in_proj_w,ipw, out_proj_w,opw, f1_w,f1w, f2_w,f2w, a1_w,a1w);
    // 2. q = query @ wq^T + bq
    mgemm_kernel<0><<<dim3(256, 2), 256, 0, stream>>>(wcat, 1024, ipw, 256, in_proj_b, qbuf, 256, 256, nullptr, nullptr, nullptr);
    // 3. kv = weighted @ [wk;wv]^T + b
    gemm256p_kernel<0><<<dim3(512, 2), 512, 0, stream>>>(wcat, 256, ipw+65536, 256, in_proj_b+256, kvbuf, 512, 256);
    // 4. FUSED attention + out_proj + LN+FiLM -> wcat entry rows
    attnop_kernel<<<2048, 256, 0, stream>>>(qbuf, kvbuf, wcat, opw, out_proj_b,
        regime, sg_w, sg_b, sb_w, sb_b, ln1_g, ln1_b);
    // 5. h = gelu(cat @ f1^T + b) -> hbuf
    gemm256p_kernel<1><<<dim3(128, 4), 512, 0, stream>>>(wcat, 1024, f1w, 1024, f1_b, hbuf, 1024, 1024);
    // 6. alignment = sigmoid(gelu(cat @ a1^T + b) @ a2^T + b)  — wcat L2/L3-hot after f1
    mgemm_kernel<2><<<dim3(256, 1), 256, 0, stream>>>(wcat, 1024, a1w, 1024, a1_b, qbuf, 128, 1024, a2_w, a2_b, out_align);
    // 7. t1 = h @ f2^T + b
    gemm256p_kernel<0><<<dim3(128, 2), 512, 0, stream>>>(hbuf, 1024, f2w, 1024, f2_b, t1buf, 512, 1024);
    // 8. fused = LN(t1) -> out
    ln2_kernel<<<NB, 256, 0, stream>>>(t1buf, ln2_g, ln2_b, out_fused);
}